// Round 1
// baseline (1222.441 us; speedup 1.0000x reference)
//
#include <hip/hip_runtime.h>

// RecurrentLinearAttentionPPLM: N=32,H=16,D=64,M=64,T=2048
// Outputs (concatenated in d_out): V [N,H,M], K_cat [N,H,D,T+1], V_cat [N,H,M,T+1]

#define TT   2048
#define TP1  2049
#define DD   64
#define MM   64
#define NHEADS 512
#define EPSF 1e-6f

__device__ __forceinline__ float feat(float x) {
    // elu(x)+1 : x>0 ? x+1 : exp(x)
    return x > 0.0f ? x + 1.0f : expf(x);
}

__global__ __launch_bounds__(256, 2)
void rla_fused_kernel(const float* __restrict__ query,
                      const float* __restrict__ key,
                      const float* __restrict__ value,
                      const float* __restrict__ k_hist,
                      const float* __restrict__ v_hist,
                      float* __restrict__ out)
{
    const int hh   = blockIdx.x;     // head index 0..511
    const int tid  = threadIdx.x;    // 0..255
    const int lane = tid & 63;
    const int wave = tid >> 6;

    float* outV  = out;                                   // [NH, MM]
    float* outK  = out + (size_t)NHEADS * MM;             // [NH, DD, TP1]
    float* outVc = outK + (size_t)NHEADS * DD * TP1;      // [NH, MM, TP1]

    const float* kh = k_hist + (size_t)hh * DD * TT;
    const float* vh = v_hist + (size_t)hh * MM * TT;
    float* kc = outK  + (size_t)hh * DD * TP1;
    float* vc = outVc + (size_t)hh * MM * TP1;

    __shared__ float Qs[DD];
    __shared__ float Ks[DD];
    __shared__ float Vs[MM];
    __shared__ float wparts[MM * 4];
    __shared__ float sred[4];

    if (tid < DD) {
        Qs[tid] = feat(query[hh * DD + tid]);
        Ks[tid] = feat(key[hh * DD + tid]);
        Vs[tid] = value[hh * MM + tid];
    }
    __syncthreads();

    float acc[MM];
#pragma unroll
    for (int m = 0; m < MM; ++m) acc[m] = 0.0f;
    float ssum = 0.0f;

    // 8 chunks of 256 time columns; thread owns column t = chunk*256 + tid
    for (int chunk = 0; chunk < TT / 256; ++chunk) {
        const int t = chunk * 256 + tid;

        // s_t = sum_d Q_d * K[d,t]; copy k_hist -> K_cat
        float s = 0.0f;
#pragma unroll
        for (int d = 0; d < DD; ++d) {
            float val = kh[d * TT + t];
            s += Qs[d] * val;
            kc[d * TP1 + t] = val;
        }
        ssum += s;

        // acc[m] += s_t * V[m,t]; copy v_hist -> V_cat
#pragma unroll
        for (int m = 0; m < MM; ++m) {
            float v = vh[m * TT + t];
            acc[m] += s * v;
            vc[m * TP1 + t] = v;
        }
    }

    // ---- block-reduce ssum (S over history columns) ----
    float r = ssum;
#pragma unroll
    for (int off = 32; off > 0; off >>= 1) r += __shfl_xor(r, off);
    if (lane == 0) sred[wave] = r;
    __syncthreads();
    const float S_hist = sred[0] + sred[1] + sred[2] + sred[3];

    // s for the appended current-step column: Q . feat(K)
    float s_last = 0.0f;
#pragma unroll
    for (int d = 0; d < DD; ++d) s_last += Qs[d] * Ks[d];

    const float Z = 1.0f / (S_hist + s_last + EPSF);

    // ---- reduce acc[m] across 256 threads ----
#pragma unroll
    for (int m = 0; m < MM; ++m) {
        float a = acc[m];
#pragma unroll
        for (int off = 32; off > 0; off >>= 1) a += __shfl_xor(a, off);
        if (lane == 0) wparts[m * 4 + wave] = a;
    }
    __syncthreads();

    if (tid < MM) {
        const float v4 = wparts[tid * 4 + 0] + wparts[tid * 4 + 1] +
                         wparts[tid * 4 + 2] + wparts[tid * 4 + 3];
        // output V (normalized, including current-step column contribution)
        outV[hh * MM + tid] = (v4 + s_last * Vs[tid]) * Z;
        // appended last columns of K_cat / V_cat
        kc[tid * TP1 + TT] = Ks[tid];
        vc[tid * TP1 + TT] = Vs[tid];
    }
}

extern "C" void kernel_launch(void* const* d_in, const int* in_sizes, int n_in,
                              void* d_out, int out_size, void* d_ws, size_t ws_size,
                              hipStream_t stream) {
    const float* query  = (const float*)d_in[0];
    const float* key    = (const float*)d_in[1];
    const float* value  = (const float*)d_in[2];
    const float* k_hist = (const float*)d_in[3];
    const float* v_hist = (const float*)d_in[4];
    float* out = (float*)d_out;

    hipLaunchKernelGGL(rla_fused_kernel, dim3(NHEADS), dim3(256), 0, stream,
                       query, key, value, k_hist, v_hist, out);
}